// Round 1
// baseline (77.915 us; speedup 1.0000x reference)
//
#include <hip/hip_runtime.h>

#define KAPPA 1.0f

// Kernel 1: column-sum of [N, 256] fp32 matrix into per-block partials.
// Each thread grid-strides over float4 elements; since the stride is a
// multiple of 64 (float4s per row), each thread's accumulator maps to a
// fixed group of 4 columns (i % 64 invariant).
__global__ __launch_bounds__(1024) void hub_colsum_kernel(
    const float* __restrict__ emb, float4* __restrict__ partial, int total_f4) {
    __shared__ float4 lds[1024];

    const float4* __restrict__ in = reinterpret_cast<const float4*>(emb);
    float4 acc = make_float4(0.f, 0.f, 0.f, 0.f);

    const int stride = gridDim.x * blockDim.x;
    for (int i = blockIdx.x * blockDim.x + threadIdx.x; i < total_f4; i += stride) {
        float4 v = in[i];
        acc.x += v.x; acc.y += v.y; acc.z += v.z; acc.w += v.w;
    }

    lds[threadIdx.x] = acc;
    __syncthreads();

    // Tree reduce: strides 512,256,128,64 are all multiples of 64, so
    // combined threads share the same column group.
    #pragma unroll
    for (int s = 512; s >= 64; s >>= 1) {
        if (threadIdx.x < (unsigned)s) {
            float4 o = lds[threadIdx.x + s];
            float4 m = lds[threadIdx.x];
            m.x += o.x; m.y += o.y; m.z += o.z; m.w += o.w;
            lds[threadIdx.x] = m;
        }
        __syncthreads();
    }

    if (threadIdx.x < 64) {
        // Row-major partials: partial[block][64 float4s] = 256 columns.
        partial[(size_t)blockIdx.x * 64 + threadIdx.x] = lds[threadIdx.x];
    }
}

// Kernel 2: reduce nb partial rows (nb x 64 float4s), then loss = -kappa*p0*dot(s,s).
__global__ __launch_bounds__(256) void hub_finalize_kernel(
    const float4* __restrict__ partial, const float* __restrict__ p_value,
    float* __restrict__ out, int nb) {
    __shared__ float4 lds[256];

    float4 acc = make_float4(0.f, 0.f, 0.f, 0.f);
    const int total = nb * 64;
    // 256 % 64 == 0 -> column group (i % 64) invariant per thread.
    for (int i = threadIdx.x; i < total; i += 256) {
        float4 v = partial[i];
        acc.x += v.x; acc.y += v.y; acc.z += v.z; acc.w += v.w;
    }
    lds[threadIdx.x] = acc;
    __syncthreads();

    if (threadIdx.x < 64) {
        float4 a = lds[threadIdx.x];
        float4 b = lds[threadIdx.x + 64];
        float4 c = lds[threadIdx.x + 128];
        float4 d = lds[threadIdx.x + 192];
        float sx = a.x + b.x + c.x + d.x;
        float sy = a.y + b.y + c.y + d.y;
        float sz = a.z + b.z + c.z + d.z;
        float sw = a.w + b.w + c.w + d.w;
        float dotp = sx * sx + sy * sy + sz * sz + sw * sw;

        // Wave-level reduce across the 64 lanes of wave 0 (all active).
        #pragma unroll
        for (int off = 32; off > 0; off >>= 1)
            dotp += __shfl_down(dotp, off);

        if (threadIdx.x == 0)
            out[0] = -KAPPA * p_value[0] * dotp;
    }
}

extern "C" void kernel_launch(void* const* d_in, const int* in_sizes, int n_in,
                              void* d_out, int out_size, void* d_ws, size_t ws_size,
                              hipStream_t stream) {
    const float* emb     = (const float*)d_in[0];   // [N, 256] fp32
    const float* p_value = (const float*)d_in[1];   // [1] fp32
    float* out           = (float*)d_out;           // scalar fp32

    const int n_elems  = in_sizes[0];               // N * 256
    const int total_f4 = n_elems / 4;               // float4 count

    // Each block emits 64 float4 partials = 1 KiB. Clamp to workspace.
    int nb = 512;
    size_t need_per_block = 64 * sizeof(float4);    // 1024 B
    if ((size_t)nb * need_per_block > ws_size) {
        nb = (int)(ws_size / need_per_block);
        if (nb < 1) nb = 1;
    }

    float4* partial = (float4*)d_ws;

    hub_colsum_kernel<<<nb, 1024, 0, stream>>>(emb, partial, total_f4);
    hub_finalize_kernel<<<1, 256, 0, stream>>>(partial, p_value, out, nb);
}

// Round 2
// 57.285 us; speedup vs baseline: 1.3601x; 1.3601x over previous
//
#include <hip/hip_runtime.h>

#define KAPPA 1.0f

// Kernel 1: column-sum of [N, 256] fp32 matrix into per-block partials.
// Each thread grid-strides over float4 elements; since the stride is a
// multiple of 64 (float4s per row), each thread's accumulator maps to a
// fixed group of 4 columns (i % 64 invariant).
__global__ __launch_bounds__(1024) void hub_colsum_kernel(
    const float* __restrict__ emb, float4* __restrict__ partial, int total_f4) {
    __shared__ float4 lds[1024];

    const float4* __restrict__ in = reinterpret_cast<const float4*>(emb);
    float4 acc = make_float4(0.f, 0.f, 0.f, 0.f);

    const int stride = gridDim.x * blockDim.x;
    #pragma unroll 4
    for (int i = blockIdx.x * blockDim.x + threadIdx.x; i < total_f4; i += stride) {
        float4 v = in[i];
        acc.x += v.x; acc.y += v.y; acc.z += v.z; acc.w += v.w;
    }

    lds[threadIdx.x] = acc;
    __syncthreads();

    // Tree reduce: strides 512,256,128,64 are all multiples of 64, so
    // combined threads share the same column group.
    #pragma unroll
    for (int s = 512; s >= 64; s >>= 1) {
        if (threadIdx.x < (unsigned)s) {
            float4 o = lds[threadIdx.x + s];
            float4 m = lds[threadIdx.x];
            m.x += o.x; m.y += o.y; m.z += o.z; m.w += o.w;
            lds[threadIdx.x] = m;
        }
        __syncthreads();
    }

    if (threadIdx.x < 64) {
        // Row-major partials: partial[block][64 float4s] = 256 columns.
        partial[(size_t)blockIdx.x * 64 + threadIdx.x] = lds[threadIdx.x];
    }
}

// Kernel 2: reduce nb partial rows (nb x 64 float4s), then loss = -kappa*p0*dot(s,s).
// 1024 threads: nb*64/1024 iterations, column group (i % 64) invariant since
// 1024 % 64 == 0.
__global__ __launch_bounds__(1024) void hub_finalize_kernel(
    const float4* __restrict__ partial, const float* __restrict__ p_value,
    float* __restrict__ out, int nb) {
    __shared__ float4 lds[1024];

    float4 acc = make_float4(0.f, 0.f, 0.f, 0.f);
    const int total = nb * 64;
    for (int i = threadIdx.x; i < total; i += 1024) {
        float4 v = partial[i];
        acc.x += v.x; acc.y += v.y; acc.z += v.z; acc.w += v.w;
    }
    lds[threadIdx.x] = acc;
    __syncthreads();

    // Tree reduce down to 64 entries (one full set of 256 columns).
    #pragma unroll
    for (int s = 512; s >= 64; s >>= 1) {
        if (threadIdx.x < (unsigned)s) {
            float4 o = lds[threadIdx.x + s];
            float4 m = lds[threadIdx.x];
            m.x += o.x; m.y += o.y; m.z += o.z; m.w += o.w;
            lds[threadIdx.x] = m;
        }
        __syncthreads();
    }

    if (threadIdx.x < 64) {
        float4 s4 = lds[threadIdx.x];
        float dotp = s4.x * s4.x + s4.y * s4.y + s4.z * s4.z + s4.w * s4.w;

        // Wave-level reduce across the 64 lanes of wave 0 (all active).
        #pragma unroll
        for (int off = 32; off > 0; off >>= 1)
            dotp += __shfl_down(dotp, off);

        if (threadIdx.x == 0)
            out[0] = -KAPPA * p_value[0] * dotp;
    }
}

extern "C" void kernel_launch(void* const* d_in, const int* in_sizes, int n_in,
                              void* d_out, int out_size, void* d_ws, size_t ws_size,
                              hipStream_t stream) {
    const float* emb     = (const float*)d_in[0];   // [N, 256] fp32
    const float* p_value = (const float*)d_in[1];   // [1] fp32
    float* out           = (float*)d_out;           // scalar fp32

    const int n_elems  = in_sizes[0];               // N * 256
    const int total_f4 = n_elems / 4;               // float4 count

    // Each block emits 64 float4 partials = 1 KiB. Clamp to workspace.
    int nb = 512;
    size_t need_per_block = 64 * sizeof(float4);    // 1024 B
    if ((size_t)nb * need_per_block > ws_size) {
        nb = (int)(ws_size / need_per_block);
        if (nb < 1) nb = 1;
    }

    float4* partial = (float4*)d_ws;

    hub_colsum_kernel<<<nb, 1024, 0, stream>>>(emb, partial, total_f4);
    hub_finalize_kernel<<<1, 1024, 0, stream>>>(partial, p_value, out, nb);
}